// Round 2
// baseline (939.769 us; speedup 1.0000x reference)
//
#include <hip/hip_runtime.h>
#include <hip/hip_bf16.h>

// GNN edge-conv, round 2: sort-by-dst + LDS-accumulated scatter + fused node MLP.
// ws layout (bytes):
//   hist/cursor int[50000] @ 0          (200,000)   [memset to 0]
//   seg   int[50001]       @ 200,064    (200,004)
//   perm  int[800000]      @ 400,128    (3,200,000)
//   sdst  int[800000]      @ 3,600,128  (3,200,000)
//   xb    bf16[50000][128] @ 6,800,128  (12,800,000)
//   hb    bf16[50000][128] @ 19,600,128 (12,800,000)
//   w1f   @ 32,400,128 (131,072)
//   w2f   @ 32,531,200 (65,536)
//   w3f   @ 32,596,736 (65,536)
//   w4f   @ 32,662,272 (12,288)
//   b4p   @ 32,674,560 (192)
//   flag  @ 32,674,752 (4)
// total ~32.7 MB

typedef short bf16x8 __attribute__((ext_vector_type(8)));
typedef float f32x4 __attribute__((ext_vector_type(4)));

#define N_NODES 50000
#define N_EDGES 800000
#define NB 32  // nodes per block in fused kernel

__device__ __forceinline__ unsigned short f2bf(float f) {
  unsigned u = __builtin_bit_cast(unsigned, f);
  u = u + 0x7fffu + ((u >> 16) & 1u);  // RNE
  return (unsigned short)(u >> 16);
}

__device__ __forceinline__ int ld_src(const int* ei, int m64, int e) {
  return m64 ? ei[2 * e] : ei[e];
}
__device__ __forceinline__ int ld_dst(const int* ei, int m64, int e) {
  return m64 ? ei[2 * N_EDGES + 2 * e] : ei[N_EDGES + e];
}

__global__ void k_prep_xb(const float* __restrict__ x, unsigned short* __restrict__ xb) {
  long i = ((long)blockIdx.x * 256 + threadIdx.x) * 4;
  float4 v = *(const float4*)(x + i);
  ushort4 o;
  o.x = f2bf(v.x); o.y = f2bf(v.y); o.z = f2bf(v.z); o.w = f2bf(v.w);
  *(ushort4*)(xb + i) = o;
}

// Pack W into MFMA B-fragment order: [ct][ks][lane][i], value = W[ks*32+(lane>>4)*8+i][ct*16+(lane&15)]
__device__ __forceinline__ void fill8(unsigned short* dst, const float* W, int f, int C) {
  int i = f & 7, lane = (f >> 3) & 63, ks = (f >> 9) & 7, ct = f >> 12;
  int k = ks * 32 + (lane >> 4) * 8 + i;
  int c = ct * 16 + (lane & 15);
  dst[f] = f2bf(W[k * C + c]);
}

__global__ void k_prep_frags(const float* __restrict__ W1, const float* __restrict__ W2,
                             const float* __restrict__ W3, const float* __restrict__ W4,
                             const float* __restrict__ b4,
                             unsigned short* __restrict__ w1f, unsigned short* __restrict__ w2f,
                             unsigned short* __restrict__ w3f, unsigned short* __restrict__ w4f,
                             float* __restrict__ b4p, int* __restrict__ flagp,
                             const int* __restrict__ ei) {
  int gid = blockIdx.x * 256 + threadIdx.x;
  if (gid < 65536) {
    fill8(w1f, W1, gid, 256);                        // W1 [256][256], CT=16 KS=8
  } else if (gid < 98304) {
    fill8(w3f, W3, gid - 65536, 128);                // W3 [256][128], CT=8 KS=8
  } else if (gid < 131072) {
    fill8(w2f, W2, gid - 98304, 128);                // W2 [256][128], CT=8 KS=8
  } else if (gid < 137216) {                         // W4 [128][40] pad to 48 cols, CT=3 KS=4
    int f = gid - 131072;
    int i = f & 7, lane = (f >> 3) & 63, ks = (f >> 9) & 3, ct = f >> 11;
    int k = ks * 32 + (lane >> 4) * 8 + i;
    int c = ct * 16 + (lane & 15);
    w4f[f] = (c < 40) ? f2bf(W4[k * 40 + c]) : (unsigned short)0;
  } else if (gid < 137264) {
    int c = gid - 137216;
    b4p[c] = (c < 40) ? b4[c] : 0.f;
  } else if (gid == 137264) {
    *flagp = (ei[1] == 0 && ei[3] == 0 && ei[5] == 0 && ei[7] == 0) ? 1 : 0;
  }
}

__global__ void k_hist(const int* __restrict__ ei, const int* __restrict__ flagp,
                       int* __restrict__ hist) {
  int e = blockIdx.x * 256 + threadIdx.x;
  int d = ld_dst(ei, *flagp, e);
  atomicAdd(&hist[d], 1);
}

// Single-block exclusive scan of hist[50000] -> seg; hist becomes cursor (in-place).
__global__ __launch_bounds__(256) void k_scan(int* __restrict__ hist, int* __restrict__ seg) {
  __shared__ int ps[256];
  const int t = threadIdx.x;
  const int base = t * 196;
  int s = 0;
  for (int i = 0; i < 196; ++i) {
    int idx = base + i;
    if (idx < N_NODES) s += hist[idx];
  }
  ps[t] = s;
  __syncthreads();
  for (int off = 1; off < 256; off <<= 1) {
    int v = (t >= off) ? ps[t - off] : 0;
    __syncthreads();
    ps[t] += v;
    __syncthreads();
  }
  int run = (t == 0) ? 0 : ps[t - 1];
  for (int i = 0; i < 196; ++i) {
    int idx = base + i;
    if (idx < N_NODES) {
      int h = hist[idx];
      seg[idx] = run;
      hist[idx] = run;  // cursor
      run += h;
    }
  }
  if (t == 255) seg[N_NODES] = run;
}

__global__ void k_scatter(const int* __restrict__ ei, const int* __restrict__ flagp,
                          int* __restrict__ cursor, int* __restrict__ perm,
                          int* __restrict__ sdst) {
  int e = blockIdx.x * 256 + threadIdx.x;
  int d = ld_dst(ei, *flagp, e);
  int pos = atomicAdd(&cursor[d], 1);
  perm[pos] = e;
  sdst[pos] = d;
}

// Fused: eh = relu([x_src,x_dst]@W1+b1) for this block's nodes' edges (sorted by dst),
// reduce into LDS acc, then h = relu(mean@W2+b2) -> hb. No global atomics.
// 512 threads = 8 waves; wave owns 2 of 16 col-tiles of the 256-wide MLP1.
__global__ __launch_bounds__(512, 2) void k_edge_fused(
    const unsigned short* __restrict__ xb, const int* __restrict__ ei,
    const int* __restrict__ perm, const int* __restrict__ sdst, const int* __restrict__ seg,
    const unsigned short* __restrict__ w1f, const float* __restrict__ b1,
    const unsigned short* __restrict__ w2f, const float* __restrict__ b2,
    unsigned short* __restrict__ hb, const int* __restrict__ flagp) {
  __shared__ __attribute__((aligned(16))) short Et[128 * 256];     // 64 KB, XOR-swizzled
  __shared__ __attribute__((aligned(16))) float acc[NB + 1][260];  // 34.3 KB, padded stride
  __shared__ int psrc[128];
  __shared__ int pd[128];
  __shared__ float invs[NB];
  const int t = threadIdx.x;
  const int m64 = *flagp;
  const int nb = blockIdx.x * NB;
  const int nv = min(NB, N_NODES - nb);
  const int s0 = seg[nb], s1 = seg[nb + nv];
  const int w = t >> 6, l = t & 63, lr = l & 15, lh = l >> 4;

  for (int i = t; i < (NB + 1) * 260; i += 512) ((float*)acc)[i] = 0.f;

  bf16x8 B1[2][8];
#pragma unroll
  for (int ci = 0; ci < 2; ++ci)
#pragma unroll
    for (int ks = 0; ks < 8; ++ks)
      B1[ci][ks] = *(const bf16x8*)(w1f + (((2 * w + ci) * 8 + ks) * 64 + l) * 8);
  float b1c[2];
#pragma unroll
  for (int ci = 0; ci < 2; ++ci) b1c[ci] = b1[(2 * w + ci) * 16 + lr];

  const int nch = (s1 - s0 + 127) >> 7;
#pragma unroll 1
  for (int ch = 0; ch < nch; ++ch) {
    __syncthreads();  // previous chunk's consumers done before pd/Et overwrite
    if (t < 128) {
      int idx = s0 + ch * 128 + t;
      if (idx < s1) {
        int e = perm[idx];
        psrc[t] = ld_src(ei, m64, e);
        pd[t] = sdst[idx] - nb;
      } else {
        psrc[t] = 0;
        pd[t] = NB;
      }
    }
    __syncthreads();
    // stage 128 rows x 256 cols of concat(x_src, x_dst) as bf16
#pragma unroll
    for (int j = 0; j < 8; ++j) {
      int c = t + 512 * j;
      int row = c >> 5, q = c & 31, endp = q >> 4, ck = q & 15;
      int dl = pd[row];
      int node = endp ? ((dl < NB) ? (nb + dl) : 0) : psrc[row];
      int4 v = *(const int4*)(xb + ((long)node << 7) + (ck << 3));
      int off = (row << 9) + (endp << 8) + (ck << 4);
      off ^= (row & 7) << 4;
      *(int4*)((char*)Et + off) = v;
    }
    __syncthreads();
#pragma unroll 1
    for (int rt = 0; rt < 8; ++rt) {
      f32x4 a2[2] = {};
#pragma unroll
      for (int ks = 0; ks < 8; ++ks) {
        int row = (rt << 4) + lr;
        int off = (row << 9) + (ks << 6) + (lh << 4);
        off ^= (row & 7) << 4;
        bf16x8 a = *(const bf16x8*)((const char*)Et + off);
        a2[0] = __builtin_amdgcn_mfma_f32_16x16x32_bf16(a, B1[0][ks], a2[0], 0, 0, 0);
        a2[1] = __builtin_amdgcn_mfma_f32_16x16x32_bf16(a, B1[1][ks], a2[1], 0, 0, 0);
      }
      int d4[4];
#pragma unroll
      for (int r = 0; r < 4; ++r) d4[r] = pd[(rt << 4) + (lh << 2) + r];
#pragma unroll
      for (int ci = 0; ci < 2; ++ci) {
        int col = (2 * w + ci) * 16 + lr;
        float v0 = fmaxf(a2[ci][0] + b1c[ci], 0.f);
        float v1 = fmaxf(a2[ci][1] + b1c[ci], 0.f);
        float v2 = fmaxf(a2[ci][2] + b1c[ci], 0.f);
        float v3 = fmaxf(a2[ci][3] + b1c[ci], 0.f);
        // run-combine (sorted dsts): fewer LDS atomics
        float s = v0;
        int d = d4[0];
        if (d4[1] == d) s += v1; else { atomicAdd(&acc[d][col], s); d = d4[1]; s = v1; }
        if (d4[2] == d) s += v2; else { atomicAdd(&acc[d][col], s); d = d4[2]; s = v2; }
        if (d4[3] == d) s += v3; else { atomicAdd(&acc[d][col], s); d = d4[3]; s = v3; }
        atomicAdd(&acc[d][col], s);
      }
    }
  }
  __syncthreads();
  // counts -> inv
  if (t < NB) {
    float c = 0.f;
    if (t < nv) c = (float)(seg[nb + t + 1] - seg[nb + t]);
    invs[t] = (t < nv) ? (1.0f / fmaxf(c, 1.0f)) : 0.f;
  }
  __syncthreads();
  // mean rows (bf16) into Et[0..NB)x256, swizzled
#pragma unroll
  for (int j = 0; j < 2; ++j) {
    int u = t + 512 * j;
    int row = u >> 5, ck = u & 31;
    float inv = invs[row];
    short8_pack:;
    bf16x8 o;
#pragma unroll
    for (int i = 0; i < 8; ++i) o[i] = (short)f2bf(acc[row][ck * 8 + i] * inv);
    int off = (row << 9) + (ck << 4);
    off ^= (row & 7) << 4;
    *(bf16x8*)((char*)Et + off) = o;
  }
  __syncthreads();
  // node MLP: h = relu(mean@W2+b2); wave w owns col-tile w (128 cols total)
  bf16x8 B2[8];
#pragma unroll
  for (int ks = 0; ks < 8; ++ks)
    B2[ks] = *(const bf16x8*)(w2f + ((w * 8 + ks) * 64 + l) * 8);
  float b2c = b2[w * 16 + lr];
#pragma unroll
  for (int rt = 0; rt < 2; ++rt) {
    f32x4 h4 = {};
#pragma unroll
    for (int ks = 0; ks < 8; ++ks) {
      int row = (rt << 4) + lr;
      int off = (row << 9) + (ks << 6) + (lh << 4);
      off ^= (row & 7) << 4;
      bf16x8 a = *(const bf16x8*)((const char*)Et + off);
      h4 = __builtin_amdgcn_mfma_f32_16x16x32_bf16(a, B2[ks], h4, 0, 0, 0);
    }
#pragma unroll
    for (int r = 0; r < 4; ++r) {
      int row = (rt << 4) + (lh << 2) + r;
      if (row < nv) {
        float hv = fmaxf(h4[r] + b2c, 0.f);
        hb[(long)(nb + row) * 128 + w * 16 + lr] = f2bf(hv);
      }
    }
  }
}

// K3: z = relu([h_src,h_dst]@W3+b3); logits = z@W4+b4; log_softmax -> out.
__global__ __launch_bounds__(256, 2) void k_edge_head(
    const unsigned short* __restrict__ hb, const int* __restrict__ ei,
    const unsigned short* __restrict__ w3f, const float* __restrict__ b3,
    const unsigned short* __restrict__ w4f, const float* __restrict__ b4p,
    float* __restrict__ out, const int* __restrict__ flagp) {
  __shared__ __attribute__((aligned(16))) char L[49152];
  short* e2 = (short*)L;            // 32 KB
  short* zb = (short*)(L + 32768);  // 16 KB
  float* lg = (float*)L;            // 12 KB (aliases e2 after stage1)
  const int t = threadIdx.x;
  const int m64 = *flagp;
  const int eb = blockIdx.x * 64;
  const int w = t >> 6, l = t & 63, lr = l & 15, lh = l >> 4;

  bf16x8 B3[2][8];
#pragma unroll
  for (int ci = 0; ci < 2; ++ci)
#pragma unroll
    for (int ks = 0; ks < 8; ++ks)
      B3[ci][ks] = *(const bf16x8*)(w3f + (((2 * w + ci) * 8 + ks) * 64 + l) * 8);
  float b3c[2];
#pragma unroll
  for (int ci = 0; ci < 2; ++ci) b3c[ci] = b3[(2 * w + ci) * 16 + lr];

#pragma unroll
  for (int j = 0; j < 8; ++j) {
    int c = t + 256 * j;
    int row = c >> 5, q = c & 31, endp = q >> 4, ck = q & 15;
    int e = eb + row;
    int node = endp ? ld_dst(ei, m64, e) : ld_src(ei, m64, e);
    int4 v = *(const int4*)(hb + ((long)node << 7) + (ck << 3));
    int off = (row << 9) + (endp << 8) + (ck << 4);
    off ^= (row & 7) << 4;
    *(int4*)((char*)e2 + off) = v;
  }
  __syncthreads();

#pragma unroll 1
  for (int rt = 0; rt < 4; ++rt) {
    f32x4 acc[2] = {};
#pragma unroll
    for (int ks = 0; ks < 8; ++ks) {
      int row = (rt << 4) + lr;
      int off = (row << 9) + (ks << 6) + (lh << 4);
      off ^= (row & 7) << 4;
      bf16x8 a = *(const bf16x8*)((const char*)e2 + off);
#pragma unroll
      for (int ci = 0; ci < 2; ++ci)
        acc[ci] = __builtin_amdgcn_mfma_f32_16x16x32_bf16(a, B3[ci][ks], acc[ci], 0, 0, 0);
    }
#pragma unroll
    for (int ci = 0; ci < 2; ++ci) {
      int col = (2 * w + ci) * 16 + lr;
#pragma unroll
      for (int r = 0; r < 4; ++r) {
        int row = (rt << 4) + (lh << 2) + r;
        float v = fmaxf(acc[ci][r] + b3c[ci], 0.f);
        int off = (row << 8) + (col << 1);
        off ^= (row & 7) << 4;
        *(short*)((char*)zb + off) = (short)f2bf(v);
      }
    }
  }
  __syncthreads();

  bf16x8 B4[3][4];
#pragma unroll
  for (int ci = 0; ci < 3; ++ci)
#pragma unroll
    for (int ks = 0; ks < 4; ++ks)
      B4[ci][ks] = *(const bf16x8*)(w4f + ((ci * 4 + ks) * 64 + l) * 8);
  f32x4 acc2[3] = {};
#pragma unroll
  for (int ks = 0; ks < 4; ++ks) {
    int row = (w << 4) + lr;
    int off = (row << 8) + (ks << 6) + (lh << 4);
    off ^= (row & 7) << 4;
    bf16x8 a = *(const bf16x8*)((const char*)zb + off);
#pragma unroll
    for (int ci = 0; ci < 3; ++ci)
      acc2[ci] = __builtin_amdgcn_mfma_f32_16x16x32_bf16(a, B4[ci][ks], acc2[ci], 0, 0, 0);
  }
#pragma unroll
  for (int ci = 0; ci < 3; ++ci) {
    int col = ci * 16 + lr;
    float bb = b4p[col];
#pragma unroll
    for (int r = 0; r < 4; ++r) {
      int row = (w << 4) + (lh << 2) + r;
      lg[row * 48 + col] = acc2[ci][r] + bb;
    }
  }
  __syncthreads();

  const int r = t >> 2, q = t & 3;
  float v[10], mx = -1e30f;
#pragma unroll
  for (int j = 0; j < 10; ++j) {
    v[j] = lg[r * 48 + q + 4 * j];
    mx = fmaxf(mx, v[j]);
  }
  mx = fmaxf(mx, __shfl_xor(mx, 1, 64));
  mx = fmaxf(mx, __shfl_xor(mx, 2, 64));
  float s = 0.f;
#pragma unroll
  for (int j = 0; j < 10; ++j) s += __expf(v[j] - mx);
  s += __shfl_xor(s, 1, 64);
  s += __shfl_xor(s, 2, 64);
  float lse = mx + __logf(s);
#pragma unroll
  for (int j = 0; j < 10; ++j) out[(long)(eb + r) * 40 + q + 4 * j] = v[j] - lse;
}

extern "C" void kernel_launch(void* const* d_in, const int* in_sizes, int n_in,
                              void* d_out, int out_size, void* d_ws, size_t ws_size,
                              hipStream_t stream) {
  const float* x = (const float*)d_in[0];
  const int* ei = (const int*)d_in[1];
  const float* W1 = (const float*)d_in[2];
  const float* b1 = (const float*)d_in[3];
  const float* W2 = (const float*)d_in[4];
  const float* b2 = (const float*)d_in[5];
  const float* W3 = (const float*)d_in[6];
  const float* b3 = (const float*)d_in[7];
  const float* W4 = (const float*)d_in[8];
  const float* b4 = (const float*)d_in[9];
  char* ws = (char*)d_ws;
  int* hist = (int*)(ws + 0);
  int* seg = (int*)(ws + 200064);
  int* perm = (int*)(ws + 400128);
  int* sdst = (int*)(ws + 3600128);
  unsigned short* xb = (unsigned short*)(ws + 6800128);
  unsigned short* hb = (unsigned short*)(ws + 19600128);
  unsigned short* w1f = (unsigned short*)(ws + 32400128);
  unsigned short* w2f = (unsigned short*)(ws + 32531200);
  unsigned short* w3f = (unsigned short*)(ws + 32596736);
  unsigned short* w4f = (unsigned short*)(ws + 32662272);
  float* b4p = (float*)(ws + 32674560);
  int* flagp = (int*)(ws + 32674752);
  float* out = (float*)d_out;

  hipMemsetAsync(ws, 0, 200000, stream);  // hist
  k_prep_xb<<<6250, 256, 0, stream>>>(x, xb);
  k_prep_frags<<<537, 256, 0, stream>>>(W1, W2, W3, W4, b4, w1f, w2f, w3f, w4f, b4p, flagp, ei);
  k_hist<<<3125, 256, 0, stream>>>(ei, flagp, hist);
  k_scan<<<1, 256, 0, stream>>>(hist, seg);
  k_scatter<<<3125, 256, 0, stream>>>(ei, flagp, hist, perm, sdst);
  k_edge_fused<<<1563, 512, 0, stream>>>(xb, ei, perm, sdst, seg, w1f, b1, w2f, b2, hb, flagp);
  k_edge_head<<<12500, 256, 0, stream>>>(hb, ei, w3f, b3, w4f, b4p, out, flagp);
}

// Round 3
// 307.751 us; speedup vs baseline: 3.0537x; 3.0537x over previous
//
#include <hip/hip_runtime.h>
#include <hip/hip_bf16.h>

// Round 3: factor edge MLPs through per-node terms.
//   S = x@W1[0:128,:], Y' = x@W1[128:256,:]+b1   (one GEMM, N=512)
//   eh_e = relu(S[src]+Y'[dst]); agg via sorted-by-dst segment sum (reg accum)
//   mean -> h = relu(mean@W2+b2) -> [P|Q'] = h@[W3top|W3bot(+b3)]
//   z_e = relu(P[src]+Q'[dst]); logits = z@W4+b4; log_softmax
// ws (bytes):
//   hist/cursor int[50000] @0         (memset)
//   seg  int[50001]        @200064
//   bsum int[256]          @400128
//   ssrc int[800000]       @401152
//   SY   bf16[50000][512]  @3601408   (S=cols 0-255, Y'=256-511; mean overwrites Y';
//                                      PQ overwrites S: P=0-127, Q'=128-255)
//   w1f @54801408  w2f @54932480  w3f @54998016  w4f @55063552
//   b4p @55075840  flag @55076032      total ~55.1 MB

typedef short bf16x8 __attribute__((ext_vector_type(8)));
typedef float f32x4 __attribute__((ext_vector_type(4)));

#define N_NODES 50000
#define N_EDGES 800000

__device__ __forceinline__ unsigned short f2bf(float f) {
  unsigned u = __builtin_bit_cast(unsigned, f);
  u = u + 0x7fffu + ((u >> 16) & 1u);  // RNE
  return (unsigned short)(u >> 16);
}
__device__ __forceinline__ float bf2f(unsigned short h) {
  unsigned u = ((unsigned)h) << 16;
  return __builtin_bit_cast(float, u);
}
__device__ __forceinline__ int ld_src(const int* ei, int m64, int e) {
  return m64 ? ei[2 * e] : ei[e];
}
__device__ __forceinline__ int ld_dst(const int* ei, int m64, int e) {
  return m64 ? ei[2 * N_EDGES + 2 * e] : ei[N_EDGES + e];
}

__global__ void k_prep_frags(const float* __restrict__ W1, const float* __restrict__ W2,
                             const float* __restrict__ W3, const float* __restrict__ W4,
                             const float* __restrict__ b4,
                             unsigned short* __restrict__ w1f, unsigned short* __restrict__ w2f,
                             unsigned short* __restrict__ w3f, unsigned short* __restrict__ w4f,
                             float* __restrict__ b4p, int* __restrict__ flagp,
                             const int* __restrict__ ei) {
  int gid = blockIdx.x * 256 + threadIdx.x;
  if (gid < 65536) {  // w1f: Bcat1[128][512], ct32 ks4
    int i = gid & 7, lane = (gid >> 3) & 63, ks = (gid >> 9) & 3, ct = gid >> 11;
    int k = ks * 32 + (lane >> 4) * 8 + i;
    int c = ct * 16 + (lane & 15);
    float v = (c < 256) ? W1[k * 256 + c] : W1[(128 + k) * 256 + (c - 256)];
    w1f[gid] = f2bf(v);
  } else if (gid < 98304) {  // w2f: W2[256][128], ct8 ks8
    int f = gid - 65536;
    int i = f & 7, lane = (f >> 3) & 63, ks = (f >> 9) & 7, ct = f >> 12;
    int k = ks * 32 + (lane >> 4) * 8 + i;
    int c = ct * 16 + (lane & 15);
    w2f[f] = f2bf(W2[k * 128 + c]);
  } else if (gid < 131072) {  // w3f: Bcat3[128][256], ct16 ks4
    int f = gid - 98304;
    int i = f & 7, lane = (f >> 3) & 63, ks = (f >> 9) & 3, ct = f >> 11;
    int k = ks * 32 + (lane >> 4) * 8 + i;
    int c = ct * 16 + (lane & 15);
    float v = (c < 128) ? W3[k * 128 + c] : W3[(128 + k) * 128 + (c - 128)];
    w3f[f] = f2bf(v);
  } else if (gid < 137216) {  // w4f: W4[128][40->48], ct3 ks4
    int f = gid - 131072;
    int i = f & 7, lane = (f >> 3) & 63, ks = (f >> 9) & 3, ct = f >> 11;
    int k = ks * 32 + (lane >> 4) * 8 + i;
    int c = ct * 16 + (lane & 15);
    w4f[f] = (c < 40) ? f2bf(W4[k * 40 + c]) : (unsigned short)0;
  } else if (gid < 137264) {
    int c = gid - 137216;
    b4p[c] = (c < 40) ? b4[c] : 0.f;
  } else if (gid == 137264) {
    *flagp = (ei[1] == 0 && ei[3] == 0 && ei[5] == 0 && ei[7] == 0) ? 1 : 0;
  }
}

__global__ void k_hist(const int* __restrict__ ei, const int* __restrict__ flagp,
                       int* __restrict__ hist) {
  int e = blockIdx.x * 256 + threadIdx.x;
  atomicAdd(&hist[ld_dst(ei, *flagp, e)], 1);
}

__global__ __launch_bounds__(256) void k_scan_a(const int* __restrict__ hist,
                                                int* __restrict__ bsum) {
  __shared__ int ps[256];
  int t = threadIdx.x, idx = blockIdx.x * 256 + t;
  ps[t] = (idx < N_NODES) ? hist[idx] : 0;
  __syncthreads();
  for (int off = 128; off > 0; off >>= 1) {
    if (t < off) ps[t] += ps[t + off];
    __syncthreads();
  }
  if (t == 0) bsum[blockIdx.x] = ps[0];
}

__global__ __launch_bounds__(256) void k_scan_b(int* __restrict__ bsum, int* __restrict__ seg) {
  __shared__ int ps[256];
  int t = threadIdx.x;
  int v = (t < 196) ? bsum[t] : 0;
  ps[t] = v;
  __syncthreads();
  for (int off = 1; off < 256; off <<= 1) {
    int u = (t >= off) ? ps[t - off] : 0;
    __syncthreads();
    ps[t] += u;
    __syncthreads();
  }
  if (t < 196) bsum[t] = ps[t] - v;  // exclusive
  if (t == 195) seg[N_NODES] = ps[195];
}

__global__ __launch_bounds__(256) void k_scan_c(int* __restrict__ hist,
                                                const int* __restrict__ bsum,
                                                int* __restrict__ seg) {
  __shared__ int ps[256];
  int t = threadIdx.x, idx = blockIdx.x * 256 + t;
  int v = (idx < N_NODES) ? hist[idx] : 0;
  ps[t] = v;
  __syncthreads();
  for (int off = 1; off < 256; off <<= 1) {
    int u = (t >= off) ? ps[t - off] : 0;
    __syncthreads();
    ps[t] += u;
    __syncthreads();
  }
  int run = bsum[blockIdx.x] + ps[t] - v;
  if (idx < N_NODES) {
    seg[idx] = run;
    hist[idx] = run;  // becomes cursor
  }
}

__global__ void k_scatter(const int* __restrict__ ei, const int* __restrict__ flagp,
                          int* __restrict__ cursor, int* __restrict__ ssrc) {
  int e = blockIdx.x * 256 + threadIdx.x;
  int m64 = *flagp;
  int s = ld_src(ei, m64, e), d = ld_dst(ei, m64, e);
  int pos = atomicAdd(&cursor[d], 1);
  ssrc[pos] = s;
}

// SY GEMM: [S|Y'] = x @ [W1top | W1bot], +b1 on Y' cols. 64-row tiles, 8 waves.
__global__ __launch_bounds__(512, 2) void k_sy(const float* __restrict__ x,
                                               const unsigned short* __restrict__ w1f,
                                               const float* __restrict__ b1,
                                               unsigned short* __restrict__ SY) {
  __shared__ __attribute__((aligned(16))) short A[64 * 128];  // 16 KB swizzled (256B rows)
  const int t = threadIdx.x;
  const int nb = blockIdx.x * 64;
  const int nv = min(64, N_NODES - nb);
  const int w = t >> 6, l = t & 63, lr = l & 15, lh = l >> 4;

  bf16x8 B[4][4];
#pragma unroll
  for (int ci = 0; ci < 4; ++ci)
#pragma unroll
    for (int ks = 0; ks < 4; ++ks)
      B[ci][ks] = *(const bf16x8*)(w1f + (((w * 4 + ci) * 4 + ks) * 64 + l) * 8);

#pragma unroll
  for (int j = 0; j < 2; ++j) {
    int c = t + 512 * j;
    int row = c >> 4, ck = c & 15;
    int rr = (row < nv) ? row : 0;
    const float* gp = x + (long)(nb + rr) * 128 + ck * 8;
    float4 v0 = *(const float4*)gp;
    float4 v1 = *(const float4*)(gp + 4);
    bf16x8 o;
    o[0] = (short)f2bf(v0.x); o[1] = (short)f2bf(v0.y);
    o[2] = (short)f2bf(v0.z); o[3] = (short)f2bf(v0.w);
    o[4] = (short)f2bf(v1.x); o[5] = (short)f2bf(v1.y);
    o[6] = (short)f2bf(v1.z); o[7] = (short)f2bf(v1.w);
    int off = (row << 8) + (ck << 4);
    off ^= (row & 7) << 4;
    *(bf16x8*)((char*)A + off) = o;
  }
  __syncthreads();

#pragma unroll
  for (int rt = 0; rt < 4; ++rt) {
    f32x4 acc[4] = {};
#pragma unroll
    for (int ks = 0; ks < 4; ++ks) {
      int row = rt * 16 + lr;
      int off = (row << 8) + (ks << 6) + (lh << 4);
      off ^= (row & 7) << 4;
      bf16x8 a = *(const bf16x8*)((const char*)A + off);
#pragma unroll
      for (int ci = 0; ci < 4; ++ci)
        acc[ci] = __builtin_amdgcn_mfma_f32_16x16x32_bf16(a, B[ci][ks], acc[ci], 0, 0, 0);
    }
#pragma unroll
    for (int ci = 0; ci < 4; ++ci) {
      int col = (w * 4 + ci) * 16 + lr;
      float bb = (col >= 256) ? b1[col - 256] : 0.f;
#pragma unroll
      for (int r = 0; r < 4; ++r) {
        int row = rt * 16 + lh * 4 + r;
        if (row < nv) SY[(long)(nb + row) * 512 + col] = f2bf(acc[ci][r] + bb);
      }
    }
  }
}

// Segment mean of relu(S[src]+Y'[d]); one wave per node, lane owns 4 dims; no LDS.
__global__ __launch_bounds__(512) void k_edge_agg(unsigned short* __restrict__ SY,
                                                  const int* __restrict__ seg,
                                                  const int* __restrict__ ssrc) {
  const int t = threadIdx.x, w = t >> 6, l = t & 63;
  const int d = blockIdx.x * 8 + w;
  const int s0 = seg[d], s1 = seg[d + 1];
  unsigned short* Yp = SY + (long)d * 512 + 256 + l * 4;
  ushort4 yu = *(const ushort4*)Yp;
  const float y0 = bf2f(yu.x), y1 = bf2f(yu.y), y2 = bf2f(yu.z), y3 = bf2f(yu.w);
  float a0 = 0.f, a1 = 0.f, a2 = 0.f, a3 = 0.f;
  int pos = s0;
  for (; pos + 4 <= s1; pos += 4) {
    int sA = ssrc[pos], sB = ssrc[pos + 1], sC = ssrc[pos + 2], sD = ssrc[pos + 3];
    ushort4 uA = *(const ushort4*)(SY + (long)sA * 512 + l * 4);
    ushort4 uB = *(const ushort4*)(SY + (long)sB * 512 + l * 4);
    ushort4 uC = *(const ushort4*)(SY + (long)sC * 512 + l * 4);
    ushort4 uD = *(const ushort4*)(SY + (long)sD * 512 + l * 4);
    a0 += fmaxf(bf2f(uA.x) + y0, 0.f); a1 += fmaxf(bf2f(uA.y) + y1, 0.f);
    a2 += fmaxf(bf2f(uA.z) + y2, 0.f); a3 += fmaxf(bf2f(uA.w) + y3, 0.f);
    a0 += fmaxf(bf2f(uB.x) + y0, 0.f); a1 += fmaxf(bf2f(uB.y) + y1, 0.f);
    a2 += fmaxf(bf2f(uB.z) + y2, 0.f); a3 += fmaxf(bf2f(uB.w) + y3, 0.f);
    a0 += fmaxf(bf2f(uC.x) + y0, 0.f); a1 += fmaxf(bf2f(uC.y) + y1, 0.f);
    a2 += fmaxf(bf2f(uC.z) + y2, 0.f); a3 += fmaxf(bf2f(uC.w) + y3, 0.f);
    a0 += fmaxf(bf2f(uD.x) + y0, 0.f); a1 += fmaxf(bf2f(uD.y) + y1, 0.f);
    a2 += fmaxf(bf2f(uD.z) + y2, 0.f); a3 += fmaxf(bf2f(uD.w) + y3, 0.f);
  }
  for (; pos < s1; ++pos) {
    int sA = ssrc[pos];
    ushort4 uA = *(const ushort4*)(SY + (long)sA * 512 + l * 4);
    a0 += fmaxf(bf2f(uA.x) + y0, 0.f); a1 += fmaxf(bf2f(uA.y) + y1, 0.f);
    a2 += fmaxf(bf2f(uA.z) + y2, 0.f); a3 += fmaxf(bf2f(uA.w) + y3, 0.f);
  }
  float inv = 1.0f / fmaxf((float)(s1 - s0), 1.0f);
  ushort4 o;
  o.x = f2bf(a0 * inv); o.y = f2bf(a1 * inv);
  o.z = f2bf(a2 * inv); o.w = f2bf(a3 * inv);
  *(ushort4*)Yp = o;  // mean overwrites Y' (only this wave reads row d's Y half)
}

// h = relu(mean@W2+b2); [P|Q'] = h@[W3top|W3bot] (+b3 on Q'); PQ overwrites dead S slots.
__global__ __launch_bounds__(256, 2) void k_pq(unsigned short* __restrict__ SY,
                                               const unsigned short* __restrict__ w2f,
                                               const float* __restrict__ b2,
                                               const unsigned short* __restrict__ w3f,
                                               const float* __restrict__ b3) {
  __shared__ __attribute__((aligned(16))) short M[64 * 256];  // 32 KB (512B rows)
  __shared__ __attribute__((aligned(16))) short H[64 * 128];  // 16 KB (256B rows)
  const int t = threadIdx.x;
  const int nb = blockIdx.x * 64;
  const int nv = min(64, N_NODES - nb);
  const int w = t >> 6, l = t & 63, lr = l & 15, lh = l >> 4;

  bf16x8 B2[2][8];
#pragma unroll
  for (int ci = 0; ci < 2; ++ci)
#pragma unroll
    for (int ks = 0; ks < 8; ++ks)
      B2[ci][ks] = *(const bf16x8*)(w2f + (((w * 2 + ci) * 8 + ks) * 64 + l) * 8);

#pragma unroll
  for (int j = 0; j < 8; ++j) {
    int c = t + 256 * j;
    int row = c >> 5, ck = c & 31;
    int rr = (row < nv) ? row : 0;
    int4 v = *(const int4*)(SY + (long)(nb + rr) * 512 + 256 + ck * 8);
    int off = (row << 9) + (ck << 4);
    off ^= (row & 7) << 4;
    *(int4*)((char*)M + off) = v;
  }
  __syncthreads();

#pragma unroll
  for (int rt = 0; rt < 4; ++rt) {
    f32x4 acc[2] = {};
#pragma unroll
    for (int ks = 0; ks < 8; ++ks) {
      int row = rt * 16 + lr;
      int off = (row << 9) + (ks << 6) + (lh << 4);
      off ^= (row & 7) << 4;
      bf16x8 a = *(const bf16x8*)((const char*)M + off);
      acc[0] = __builtin_amdgcn_mfma_f32_16x16x32_bf16(a, B2[0][ks], acc[0], 0, 0, 0);
      acc[1] = __builtin_amdgcn_mfma_f32_16x16x32_bf16(a, B2[1][ks], acc[1], 0, 0, 0);
    }
#pragma unroll
    for (int ci = 0; ci < 2; ++ci) {
      int col = (w * 2 + ci) * 16 + lr;
      float bb = b2[col];
#pragma unroll
      for (int r = 0; r < 4; ++r) {
        int row = rt * 16 + lh * 4 + r;
        int off = (row << 8) + (col << 1);
        off ^= (row & 7) << 4;
        *(short*)((char*)H + off) = (short)f2bf(fmaxf(acc[ci][r] + bb, 0.f));
      }
    }
  }
  __syncthreads();

  bf16x8 B3[4][4];
#pragma unroll
  for (int ci = 0; ci < 4; ++ci)
#pragma unroll
    for (int ks = 0; ks < 4; ++ks)
      B3[ci][ks] = *(const bf16x8*)(w3f + (((w * 4 + ci) * 4 + ks) * 64 + l) * 8);

#pragma unroll
  for (int rt = 0; rt < 4; ++rt) {
    f32x4 acc[4] = {};
#pragma unroll
    for (int ks = 0; ks < 4; ++ks) {
      int row = rt * 16 + lr;
      int off = (row << 8) + (ks << 6) + (lh << 4);
      off ^= (row & 7) << 4;
      bf16x8 a = *(const bf16x8*)((const char*)H + off);
#pragma unroll
      for (int ci = 0; ci < 4; ++ci)
        acc[ci] = __builtin_amdgcn_mfma_f32_16x16x32_bf16(a, B3[ci][ks], acc[ci], 0, 0, 0);
    }
#pragma unroll
    for (int ci = 0; ci < 4; ++ci) {
      int col = (w * 4 + ci) * 16 + lr;
      float bb = (col >= 128) ? b3[col - 128] : 0.f;
#pragma unroll
      for (int r = 0; r < 4; ++r) {
        int row = rt * 16 + lh * 4 + r;
        if (row < nv) SY[(long)(nb + row) * 512 + col] = f2bf(acc[ci][r] + bb);
      }
    }
  }
}

// Head: z = relu(P[src]+Q'[dst]); logits = z@W4+b4; log_softmax. 64 edges/block, no LDS.
__global__ __launch_bounds__(256, 2) void k_head(const unsigned short* __restrict__ SY,
                                                 const int* __restrict__ ei,
                                                 const unsigned short* __restrict__ w4f,
                                                 const float* __restrict__ b4p,
                                                 float* __restrict__ out,
                                                 const int* __restrict__ flagp) {
  const int t = threadIdx.x, w = t >> 6, l = t & 63, lr = l & 15, lh = l >> 4;
  const int m64 = *flagp;
  const int eb = blockIdx.x * 64 + w * 16;
  const int el = eb + lr;
  const int sn = ld_src(ei, m64, el);
  const int dn = ld_dst(ei, m64, el);
  const unsigned short* Pp = SY + (long)sn * 512;
  const unsigned short* Qp = SY + (long)dn * 512 + 128;

  bf16x8 B4[3][4];
#pragma unroll
  for (int ci = 0; ci < 3; ++ci)
#pragma unroll
    for (int ks = 0; ks < 4; ++ks)
      B4[ci][ks] = *(const bf16x8*)(w4f + ((ci * 4 + ks) * 64 + l) * 8);

  f32x4 acc[3] = {};
#pragma unroll
  for (int ks = 0; ks < 4; ++ks) {
    bf16x8 p = *(const bf16x8*)(Pp + ks * 32 + lh * 8);
    bf16x8 q = *(const bf16x8*)(Qp + ks * 32 + lh * 8);
    bf16x8 a;
#pragma unroll
    for (int i = 0; i < 8; ++i)
      a[i] = (short)f2bf(fmaxf(bf2f((unsigned short)p[i]) + bf2f((unsigned short)q[i]), 0.f));
#pragma unroll
    for (int ci = 0; ci < 3; ++ci)
      acc[ci] = __builtin_amdgcn_mfma_f32_16x16x32_bf16(a, B4[ci][ks], acc[ci], 0, 0, 0);
  }

  float lg0[4], lg1[4], lg2[4];
  const bool val2 = lr < 8;
  const float bb0 = b4p[lr], bb1 = b4p[16 + lr], bb2 = b4p[32 + lr];
#pragma unroll
  for (int r = 0; r < 4; ++r) {
    lg0[r] = acc[0][r] + bb0;
    lg1[r] = acc[1][r] + bb1;
    lg2[r] = acc[2][r] + bb2;
  }
#pragma unroll
  for (int r = 0; r < 4; ++r) {
    float m = fmaxf(lg0[r], lg1[r]);
    if (val2) m = fmaxf(m, lg2[r]);
    m = fmaxf(m, __shfl_xor(m, 1, 64));
    m = fmaxf(m, __shfl_xor(m, 2, 64));
    m = fmaxf(m, __shfl_xor(m, 4, 64));
    m = fmaxf(m, __shfl_xor(m, 8, 64));
    float s = __expf(lg0[r] - m) + __expf(lg1[r] - m) + (val2 ? __expf(lg2[r] - m) : 0.f);
    s += __shfl_xor(s, 1, 64);
    s += __shfl_xor(s, 2, 64);
    s += __shfl_xor(s, 4, 64);
    s += __shfl_xor(s, 8, 64);
    float lse = m + __logf(s);
    long ob = (long)(eb + lh * 4 + r) * 40;
    out[ob + lr] = lg0[r] - lse;
    out[ob + 16 + lr] = lg1[r] - lse;
    if (val2) out[ob + 32 + lr] = lg2[r] - lse;
  }
}

extern "C" void kernel_launch(void* const* d_in, const int* in_sizes, int n_in,
                              void* d_out, int out_size, void* d_ws, size_t ws_size,
                              hipStream_t stream) {
  const float* x = (const float*)d_in[0];
  const int* ei = (const int*)d_in[1];
  const float* W1 = (const float*)d_in[2];
  const float* b1 = (const float*)d_in[3];
  const float* W2 = (const float*)d_in[4];
  const float* b2 = (const float*)d_in[5];
  const float* W3 = (const float*)d_in[6];
  const float* b3 = (const float*)d_in[7];
  const float* W4 = (const float*)d_in[8];
  const float* b4 = (const float*)d_in[9];
  char* ws = (char*)d_ws;
  int* hist = (int*)(ws + 0);
  int* seg = (int*)(ws + 200064);
  int* bsum = (int*)(ws + 400128);
  int* ssrc = (int*)(ws + 401152);
  unsigned short* SY = (unsigned short*)(ws + 3601408);
  unsigned short* w1f = (unsigned short*)(ws + 54801408);
  unsigned short* w2f = (unsigned short*)(ws + 54932480);
  unsigned short* w3f = (unsigned short*)(ws + 54998016);
  unsigned short* w4f = (unsigned short*)(ws + 55063552);
  float* b4p = (float*)(ws + 55075840);
  int* flagp = (int*)(ws + 55076032);
  float* out = (float*)d_out;

  hipMemsetAsync(ws, 0, 200000, stream);  // hist
  k_prep_frags<<<537, 256, 0, stream>>>(W1, W2, W3, W4, b4, w1f, w2f, w3f, w4f, b4p, flagp, ei);
  k_hist<<<3125, 256, 0, stream>>>(ei, flagp, hist);
  k_scan_a<<<196, 256, 0, stream>>>(hist, bsum);
  k_scan_b<<<1, 256, 0, stream>>>(bsum, seg);
  k_scan_c<<<196, 256, 0, stream>>>(hist, bsum, seg);
  k_scatter<<<3125, 256, 0, stream>>>(ei, flagp, hist, ssrc);
  k_sy<<<782, 512, 0, stream>>>(x, w1f, b1, SY);
  k_edge_agg<<<6250, 512, 0, stream>>>(SY, seg, ssrc);
  k_pq<<<782, 256, 0, stream>>>(SY, w2f, b2, w3f, b3);
  k_head<<<12500, 256, 0, stream>>>(SY, ei, w4f, b4p, out, flagp);
}